// Round 3
// baseline (195.395 us; speedup 1.0000x reference)
//
#include <hip/hip_runtime.h>
#include <math.h>

// DeepIRT forward. Dims from the reference:
#define B_   64
#define T_   256
#define M_   64
#define DK_  128
#define DV_  256
#define S_   128
#define NQR  201     // Eq rows  (q_data in [0,200])
#define NQAR 401     // Eqa rows (qa_data in [0,400])
#define NSR  2001    // Es rows  (s_data in [0,2000])

static __device__ __forceinline__ int imin(int a, int b){ return a < b ? a : b; }

static __device__ __forceinline__ float fast_tanh(float x){
  float e = __expf(2.f * x);
  return 1.f - 2.f / (e + 1.f);
}

// ---------------------------------------------------------------------------
// DPP wave64 sum: 6 dependent VALU adds, result in lane 63. No LDS pipe.
// ---------------------------------------------------------------------------
template<int CTRL, int RM>
static __device__ __forceinline__ float dppadd(float x) {
  return x + __int_as_float(
      __builtin_amdgcn_update_dpp(0, __float_as_int(x), CTRL, RM, 0xf, true));
}
static __device__ __forceinline__ float wave_sum_lane63(float x) {
  x = dppadd<0x111, 0xf>(x);  // row_shr:1
  x = dppadd<0x112, 0xf>(x);  // row_shr:2
  x = dppadd<0x114, 0xf>(x);  // row_shr:4
  x = dppadd<0x118, 0xf>(x);  // row_shr:8  -> lane15/31/47/63 hold row sums
  x = dppadd<0x142, 0xa>(x);  // row_bcast:15 -> lane31, lane63 partials
  x = dppadd<0x143, 0xc>(x);  // row_bcast:31 -> lane63 = all 64
  return x;
}

// ---------------------------------------------------------------------------
// Role: corr row + fused w2/csb rows.  4 rows/block, 1 wave/row.
// ---------------------------------------------------------------------------
__device__ void corr_role(int blk, const float* __restrict__ Eq,
                          const float* __restrict__ Km,
                          const float* __restrict__ Wsa,
                          const float* __restrict__ bsa,
                          float* __restrict__ corr,
                          float* __restrict__ w2_t,
                          float* __restrict__ csb_t)
{
  __shared__ float eq[4][DK_];
  __shared__ float cwb[4][M_];
  const int w = threadIdx.x >> 6, m = threadIdx.x & 63;
  const int i  = blk * 4 + w;
  const int ic = imin(i, NQR - 1);
  eq[w][m]      = Eq[ic * DK_ + m];
  eq[w][m + 64] = Eq[ic * DK_ + 64 + m];
  float acc = 0.f;
  const float4* kr = (const float4*)(Km + m * DK_);
  #pragma unroll 8
  for (int k4 = 0; k4 < DK_ / 4; ++k4) {
    float4 kv = kr[k4];
    acc = fmaf(eq[w][k4 * 4 + 0], kv.x, acc);
    acc = fmaf(eq[w][k4 * 4 + 1], kv.y, acc);
    acc = fmaf(eq[w][k4 * 4 + 2], kv.z, acc);
    acc = fmaf(eq[w][k4 * 4 + 3], kv.w, acc);
  }
  float mx = acc;
  #pragma unroll
  for (int off = 32; off; off >>= 1) mx = fmaxf(mx, __shfl_xor(mx, off, 64));
  float e = __expf(acc - mx);
  float ssum = e;
  #pragma unroll
  for (int off = 32; off; off >>= 1) ssum += __shfl_xor(ssum, off, 64);
  const float cw = e / ssum;
  if (i < NQR) corr[i * M_ + m] = cw;
  cwb[w][m] = cw;

  float pv = wave_sum_lane63(cw * bsa[m]);
  if (m == 63 && i < NQR) csb_t[i] = pv;

  float aw[4] = {0,0,0,0};
  for (int mm = 0; mm < M_; ++mm) {
    const float c = cwb[w][mm];
    #pragma unroll
    for (int r = 0; r < 4; ++r)
      aw[r] = fmaf(c, Wsa[(r * 64 + m) * M_ + mm], aw[r]);
  }
  if (i < NQR) {
    #pragma unroll
    for (int r = 0; r < 4; ++r) w2_t[i * DV_ + r * 64 + m] = aw[r];
  }
}

// ---------------------------------------------------------------------------
// Role: erase/add tables.
// ---------------------------------------------------------------------------
__device__ void ea_role(int blk, const float* __restrict__ Eqa,
                        const float* __restrict__ We, const float* __restrict__ be,
                        const float* __restrict__ Wa, const float* __restrict__ ba,
                        float* __restrict__ ert, float* __restrict__ adt)
{
  __shared__ float a[8][DV_];
  const int d  = threadIdx.x;
  const int i0 = blk * 8;
  #pragma unroll
  for (int r = 0; r < 8; ++r) a[r][d] = Eqa[imin(i0 + r, NQAR - 1) * DV_ + d];
  __syncthreads();
  float er[8] = {0,0,0,0,0,0,0,0}, ad[8] = {0,0,0,0,0,0,0,0};
  for (int k = 0; k < DV_; ++k) {
    float we = We[k * DV_ + d];
    float wa = Wa[k * DV_ + d];
    #pragma unroll
    for (int r = 0; r < 8; ++r) {
      er[r] = fmaf(a[r][k], we, er[r]);
      ad[r] = fmaf(a[r][k], wa, ad[r]);
    }
  }
  const float beo = be[d], bao = ba[d];
  #pragma unroll
  for (int r = 0; r < 8; ++r) {
    int i = i0 + r;
    if (i < NQAR) { ert[i * DV_ + d] = er[r] + beo; adt[i * DV_ + d] = ad[r] + bao; }
  }
}

// ---------------------------------------------------------------------------
// Role: tanh-MLP scalar tables.
// ---------------------------------------------------------------------------
__device__ void mlp_role(int blk, const float* __restrict__ E,
                         const float* __restrict__ W1, const float* __restrict__ b1,
                         const float* __restrict__ W2v, const float* __restrict__ b2,
                         float* __restrict__ outt, int nrows)
{
  __shared__ float e[8 * S_];
  __shared__ float red[8][2];
  const int tid = threadIdx.x;
  const int s = tid & 127, rh = tid >> 7;
  const int i0 = blk * 8;
  #pragma unroll
  for (int j = 0; j < 4; ++j) {
    int x = tid + j * 256;
    int row = imin(i0 + (x >> 7), nrows - 1);
    e[x] = E[row * DK_ + (x & 127)];
  }
  __syncthreads();
  float acc[4] = {0,0,0,0};
  const float* eb = e + rh * 4 * 128;
  for (int k = 0; k < DK_; ++k) {
    float wv = W1[k * S_ + s];
    #pragma unroll
    for (int r = 0; r < 4; ++r) acc[r] = fmaf(eb[r * 128 + k], wv, acc[r]);
  }
  const float b1s = b1[s], w2s = W2v[s];
  float p[4];
  #pragma unroll
  for (int r = 0; r < 4; ++r) p[r] = fast_tanh(acc[r] + b1s) * w2s;
  #pragma unroll
  for (int r = 0; r < 4; ++r) p[r] = wave_sum_lane63(p[r]);
  const int lane = tid & 63;
  const int half = s >> 6;
  if (lane == 63) {
    #pragma unroll
    for (int r = 0; r < 4; ++r) red[rh * 4 + r][half] = p[r];
  }
  __syncthreads();
  if (tid < 8) {
    int i = i0 + tid;
    if (i < nrows) outt[i] = red[tid][0] + red[tid][1] + b2[0];
  }
}

// ---------------------------------------------------------------------------
#define NB_CORR 51
#define NB_EA   51
#define NB_QD   26
#define NB_SD   251
#define NB_TOT  (NB_CORR + NB_EA + NB_QD + NB_SD)

__global__ __launch_bounds__(256) void tables_kernel(
    const float* Eq, const float* Km, const float* Wsa, const float* bsa,
    float* corr_t, float* w2_t, float* csb_t,
    const float* Eqa, const float* We, const float* be,
    const float* Wa, const float* ba, float* er_t, float* ad_t,
    const float* Wqd1, const float* bqd1, const float* Wqd, const float* bqd, float* qd_t,
    const float* Es, const float* Wsd1, const float* bsd1, const float* Wsd, const float* bsd, float* sd_t)
{
  int blk = blockIdx.x;
  if (blk < NB_CORR) { corr_role(blk, Eq, Km, Wsa, bsa, corr_t, w2_t, csb_t); return; }
  blk -= NB_CORR;
  if (blk < NB_EA)   { ea_role(blk, Eqa, We, be, Wa, ba, er_t, ad_t); return; }
  blk -= NB_EA;
  if (blk < NB_QD)   { mlp_role(blk, Eq, Wqd1, bqd1, Wqd, bqd, qd_t, NQR); return; }
  blk -= NB_QD;
  mlp_role(blk, Es, Wsd1, bsd1, Wsd, bsd, sd_t, NSR);
}

// ---------------------------------------------------------------------------
// The sequential scan, v3.
// Grid (8, B), 512-thread blocks (8 waves). xx: dq = xx>>1 (d-chunk of 64),
// mh = xx&1; wave w in 0..7 -> mg = mh*8+w in 0..15, owns 4 m-rows.
// 4096 waves total = 16 waves/CU. All 8 waves of a block share (b,dq) so
// er/ad/w2 row loads hit L1. No LDS, no barriers, no register rotation:
// t-loop unrolled x8 with two 4-step operand buffers refilled in place.
// q/qa held in per-lane registers (lane l has t=4l..4l+3), extracted with
// v_readlane -> all table offsets are scalar.
// ---------------------------------------------------------------------------
struct SOps { float4 c; float er, ad, w2; };

static __device__ __forceinline__ void fetch4(
    int ii, const int4& qq, const int4& qaq, int m0, int d,
    const float* __restrict__ corr_t, const float* __restrict__ er_t,
    const float* __restrict__ ad_t, const float* __restrict__ w2_t,
    SOps (&o)[4])
{
  const int q0 = __builtin_amdgcn_readlane(qq.x,  ii);
  const int q1 = __builtin_amdgcn_readlane(qq.y,  ii);
  const int q2 = __builtin_amdgcn_readlane(qq.z,  ii);
  const int q3 = __builtin_amdgcn_readlane(qq.w,  ii);
  const int a0 = __builtin_amdgcn_readlane(qaq.x, ii);
  const int a1 = __builtin_amdgcn_readlane(qaq.y, ii);
  const int a2 = __builtin_amdgcn_readlane(qaq.z, ii);
  const int a3 = __builtin_amdgcn_readlane(qaq.w, ii);
  o[0].c = *(const float4*)(corr_t + q0 * M_ + m0);
  o[1].c = *(const float4*)(corr_t + q1 * M_ + m0);
  o[2].c = *(const float4*)(corr_t + q2 * M_ + m0);
  o[3].c = *(const float4*)(corr_t + q3 * M_ + m0);
  o[0].er = er_t[a0 * DV_ + d];  o[0].ad = ad_t[a0 * DV_ + d];  o[0].w2 = w2_t[q0 * DV_ + d];
  o[1].er = er_t[a1 * DV_ + d];  o[1].ad = ad_t[a1 * DV_ + d];  o[1].w2 = w2_t[q1 * DV_ + d];
  o[2].er = er_t[a2 * DV_ + d];  o[2].ad = ad_t[a2 * DV_ + d];  o[2].w2 = w2_t[q2 * DV_ + d];
  o[3].er = er_t[a3 * DV_ + d];  o[3].ad = ad_t[a3 * DV_ + d];  o[3].w2 = w2_t[q3 * DV_ + d];
}

static __device__ __forceinline__ float step1(float (&Mv)[4], const SOps& o)
{
  float r0 = Mv[0] * o.c.x;
  float r1 = Mv[1] * o.c.y;
  r0 = fmaf(Mv[2], o.c.z, r0);
  r1 = fmaf(Mv[3], o.c.w, r1);
  // Mv = Mv*(1 - c*er) + c*ad  computed as fma(c, ad - er*Mv, Mv)
  Mv[0] = fmaf(o.c.x, fmaf(-o.er, Mv[0], o.ad), Mv[0]);
  Mv[1] = fmaf(o.c.y, fmaf(-o.er, Mv[1], o.ad), Mv[1]);
  Mv[2] = fmaf(o.c.z, fmaf(-o.er, Mv[2], o.ad), Mv[2]);
  Mv[3] = fmaf(o.c.w, fmaf(-o.er, Mv[3], o.ad), Mv[3]);
  return wave_sum_lane63((r0 + r1) * o.w2);
}

__global__ __launch_bounds__(512) void scan_kernel(
    const int* __restrict__ q_data, const int* __restrict__ qa_data,
    const float* __restrict__ corr_t, const float* __restrict__ er_t,
    const float* __restrict__ ad_t, const float* __restrict__ w2_t,
    const float* __restrict__ Vm, float* __restrict__ sa_part)
{
  const int b  = blockIdx.y;
  const int xx = blockIdx.x;     // 0..7
  const int dq = xx >> 1;        // d chunk 0..3
  const int mh = xx & 1;
  const int tid = threadIdx.x;
  const int dl  = tid & 63;
  const int w   = tid >> 6;      // wave in block, 0..7
  const int mg  = mh * 8 + w;    // m group 0..15
  const int m0  = __builtin_amdgcn_readfirstlane(mg * 4);
  const int d   = dq * 64 + dl;

  // per-lane q/qa storage: lane l holds t = 4l..4l+3
  const int4 qq  = ((const int4*)(q_data  + b * T_))[dl];
  const int4 qaq = ((const int4*)(qa_data + b * T_))[dl];

  float Mv[4];
  #pragma unroll
  for (int j = 0; j < 4; ++j) Mv[j] = Vm[(m0 + j) * DV_ + d];

  float* baseP = sa_part + ((dq * 16 + mg) * B_ + b) * T_;

  SOps A[4], B[4];
  fetch4(0, qq, qaq, m0, d, corr_t, er_t, ad_t, w2_t, A);
  fetch4(1, qq, qaq, m0, d, corr_t, er_t, ad_t, w2_t, B);

  for (int i = 0; i < 64; i += 2) {
    float4 pA;
    pA.x = step1(Mv, A[0]);
    pA.y = step1(Mv, A[1]);
    pA.z = step1(Mv, A[2]);
    pA.w = step1(Mv, A[3]);
    fetch4((i + 2) & 63, qq, qaq, m0, d, corr_t, er_t, ad_t, w2_t, A);
    if (dl == 63) *(float4*)(baseP + 4 * i) = pA;

    float4 pB;
    pB.x = step1(Mv, B[0]);
    pB.y = step1(Mv, B[1]);
    pB.z = step1(Mv, B[2]);
    pB.w = step1(Mv, B[3]);
    fetch4((i + 3) & 63, qq, qaq, m0, d, corr_t, er_t, ad_t, w2_t, B);
    if (dl == 63) *(float4*)(baseP + 4 * i + 4) = pB;
  }
}

// ---------------------------------------------------------------------------
// out[b,t] = sigmoid( 3*(sum of 64 sa partials + csb[q]) - qd[q] - sd[s] )
// sa_part layout: [p in 0..63][b][t] -> coalesced reads per p-slice.
// ---------------------------------------------------------------------------
__global__ __launch_bounds__(256) void final_kernel(
    const int* __restrict__ q_data, const int* __restrict__ s_data,
    const float* __restrict__ sa_part, const float* __restrict__ csb_t,
    const float* __restrict__ qd_t, const float* __restrict__ sd_t,
    float* __restrict__ out)
{
  const int b = blockIdx.x, t = threadIdx.x;
  float s = 0.f;
  #pragma unroll
  for (int p = 0; p < 64; ++p) s += sa_part[(p * B_ + b) * T_ + t];
  const int bt = b * T_ + t;
  const int q  = q_data[bt];
  const int si = s_data[bt];
  const float sa = s + csb_t[q];
  const float z = 3.f * sa - qd_t[q] - sd_t[si];
  out[bt] = 1.f / (1.f + __expf(-z));
}

// ---------------------------------------------------------------------------
extern "C" void kernel_launch(void* const* d_in, const int* in_sizes, int n_in,
                              void* d_out, int out_size, void* d_ws, size_t ws_size,
                              hipStream_t stream)
{
  const int*   q_data = (const int*)d_in[0];
  const int*   qa_data= (const int*)d_in[1];
  const int*   s_data = (const int*)d_in[2];
  const float* Km     = (const float*)d_in[3];
  const float* Vm     = (const float*)d_in[4];
  const float* Eq     = (const float*)d_in[5];
  const float* Eqa    = (const float*)d_in[6];
  const float* Es     = (const float*)d_in[7];
  const float* We     = (const float*)d_in[8];
  const float* be     = (const float*)d_in[9];
  const float* Wa     = (const float*)d_in[10];
  const float* ba     = (const float*)d_in[11];
  const float* Wsa    = (const float*)d_in[12];
  const float* bsa    = (const float*)d_in[13];
  const float* Wqd1   = (const float*)d_in[14];
  const float* bqd1   = (const float*)d_in[15];
  const float* Wqd    = (const float*)d_in[16];
  const float* bqd    = (const float*)d_in[17];
  const float* Wsd1   = (const float*)d_in[18];
  const float* bsd1   = (const float*)d_in[19];
  const float* Wsd    = (const float*)d_in[20];
  const float* bsd    = (const float*)d_in[21];
  float* out = (float*)d_out;

  // workspace layout (floats); total ~5.3 MB
  float* wsf    = (float*)d_ws;
  float* corr_t = wsf;                       // 201*64   = 12864
  float* w2_t   = corr_t + NQR * M_;         // 201*256  = 51456
  float* csb_t  = w2_t + NQR * DV_;          // 201 -> pad 204
  float* er_t   = csb_t + 204;               // 401*256  = 102656
  float* ad_t   = er_t + NQAR * DV_;         // 102656
  float* qd_t   = ad_t + NQAR * DV_;         // 201 -> pad 204
  float* sd_t   = qd_t + 204;                // 2001 -> pad 2004
  float* sa_p   = sd_t + 2004;               // 64*64*256 = 1048576

  tables_kernel<<<NB_TOT, 256, 0, stream>>>(
      Eq, Km, Wsa, bsa, corr_t, w2_t, csb_t,
      Eqa, We, be, Wa, ba, er_t, ad_t,
      Wqd1, bqd1, Wqd, bqd, qd_t,
      Es, Wsd1, bsd1, Wsd, bsd, sd_t);
  scan_kernel<<<dim3(8, B_), 512, 0, stream>>>(q_data, qa_data, corr_t, er_t, ad_t, w2_t, Vm, sa_p);
  final_kernel<<<B_, 256, 0, stream>>>(q_data, s_data, sa_p, csb_t, qd_t, sd_t, out);
}

// Round 4
// 173.561 us; speedup vs baseline: 1.1258x; 1.1258x over previous
//
#include <hip/hip_runtime.h>
#include <math.h>

// DeepIRT forward. Dims from the reference:
#define B_   64
#define T_   256
#define M_   64
#define DK_  128
#define DV_  256
#define S_   128
#define NQR  201     // Eq rows  (q_data in [0,200])
#define NQAR 401     // Eqa rows (qa_data in [0,400])
#define NSR  2001    // Es rows  (s_data in [0,2000])

static __device__ __forceinline__ int imin(int a, int b){ return a < b ? a : b; }

static __device__ __forceinline__ float fast_tanh(float x){
  float e = __expf(2.f * x);
  return 1.f - 2.f / (e + 1.f);
}

// ---------------------------------------------------------------------------
// DPP wave64 sum: 6 dependent VALU adds, result in lane 63. No LDS pipe.
// ---------------------------------------------------------------------------
template<int CTRL, int RM>
static __device__ __forceinline__ float dppadd(float x) {
  return x + __int_as_float(
      __builtin_amdgcn_update_dpp(0, __float_as_int(x), CTRL, RM, 0xf, true));
}
static __device__ __forceinline__ float wave_sum_lane63(float x) {
  x = dppadd<0x111, 0xf>(x);  // row_shr:1
  x = dppadd<0x112, 0xf>(x);  // row_shr:2
  x = dppadd<0x114, 0xf>(x);  // row_shr:4
  x = dppadd<0x118, 0xf>(x);  // row_shr:8  -> lane15/31/47/63 hold row sums
  x = dppadd<0x142, 0xa>(x);  // row_bcast:15 -> lane31, lane63 partials
  x = dppadd<0x143, 0xc>(x);  // row_bcast:31 -> lane63 = all 64
  return x;
}

// ---------------------------------------------------------------------------
// Role: corr row + fused w2/csb rows.  4 rows/block, 1 wave/row.
// ---------------------------------------------------------------------------
__device__ void corr_role(int blk, const float* __restrict__ Eq,
                          const float* __restrict__ Km,
                          const float* __restrict__ Wsa,
                          const float* __restrict__ bsa,
                          float* __restrict__ corr,
                          float* __restrict__ w2_t,
                          float* __restrict__ csb_t)
{
  __shared__ float eq[4][DK_];
  __shared__ float cwb[4][M_];
  const int w = threadIdx.x >> 6, m = threadIdx.x & 63;
  const int i  = blk * 4 + w;
  const int ic = imin(i, NQR - 1);
  eq[w][m]      = Eq[ic * DK_ + m];
  eq[w][m + 64] = Eq[ic * DK_ + 64 + m];
  float acc = 0.f;
  const float4* kr = (const float4*)(Km + m * DK_);
  #pragma unroll 8
  for (int k4 = 0; k4 < DK_ / 4; ++k4) {
    float4 kv = kr[k4];
    acc = fmaf(eq[w][k4 * 4 + 0], kv.x, acc);
    acc = fmaf(eq[w][k4 * 4 + 1], kv.y, acc);
    acc = fmaf(eq[w][k4 * 4 + 2], kv.z, acc);
    acc = fmaf(eq[w][k4 * 4 + 3], kv.w, acc);
  }
  float mx = acc;
  #pragma unroll
  for (int off = 32; off; off >>= 1) mx = fmaxf(mx, __shfl_xor(mx, off, 64));
  float e = __expf(acc - mx);
  float ssum = e;
  #pragma unroll
  for (int off = 32; off; off >>= 1) ssum += __shfl_xor(ssum, off, 64);
  const float cw = e / ssum;
  if (i < NQR) corr[i * M_ + m] = cw;
  cwb[w][m] = cw;

  float pv = wave_sum_lane63(cw * bsa[m]);
  if (m == 63 && i < NQR) csb_t[i] = pv;

  float aw[4] = {0,0,0,0};
  for (int mm = 0; mm < M_; ++mm) {
    const float c = cwb[w][mm];
    #pragma unroll
    for (int r = 0; r < 4; ++r)
      aw[r] = fmaf(c, Wsa[(r * 64 + m) * M_ + mm], aw[r]);
  }
  if (i < NQR) {
    #pragma unroll
    for (int r = 0; r < 4; ++r) w2_t[i * DV_ + r * 64 + m] = aw[r];
  }
}

// ---------------------------------------------------------------------------
// Role: erase/add tables.
// ---------------------------------------------------------------------------
__device__ void ea_role(int blk, const float* __restrict__ Eqa,
                        const float* __restrict__ We, const float* __restrict__ be,
                        const float* __restrict__ Wa, const float* __restrict__ ba,
                        float* __restrict__ ert, float* __restrict__ adt)
{
  __shared__ float a[8][DV_];
  const int d  = threadIdx.x;
  const int i0 = blk * 8;
  #pragma unroll
  for (int r = 0; r < 8; ++r) a[r][d] = Eqa[imin(i0 + r, NQAR - 1) * DV_ + d];
  __syncthreads();
  float er[8] = {0,0,0,0,0,0,0,0}, ad[8] = {0,0,0,0,0,0,0,0};
  for (int k = 0; k < DV_; ++k) {
    float we = We[k * DV_ + d];
    float wa = Wa[k * DV_ + d];
    #pragma unroll
    for (int r = 0; r < 8; ++r) {
      er[r] = fmaf(a[r][k], we, er[r]);
      ad[r] = fmaf(a[r][k], wa, ad[r]);
    }
  }
  const float beo = be[d], bao = ba[d];
  #pragma unroll
  for (int r = 0; r < 8; ++r) {
    int i = i0 + r;
    if (i < NQAR) { ert[i * DV_ + d] = er[r] + beo; adt[i * DV_ + d] = ad[r] + bao; }
  }
}

// ---------------------------------------------------------------------------
// Role: tanh-MLP scalar tables.
// ---------------------------------------------------------------------------
__device__ void mlp_role(int blk, const float* __restrict__ E,
                         const float* __restrict__ W1, const float* __restrict__ b1,
                         const float* __restrict__ W2v, const float* __restrict__ b2,
                         float* __restrict__ outt, int nrows)
{
  __shared__ float e[8 * S_];
  __shared__ float red[8][2];
  const int tid = threadIdx.x;
  const int s = tid & 127, rh = tid >> 7;
  const int i0 = blk * 8;
  #pragma unroll
  for (int j = 0; j < 4; ++j) {
    int x = tid + j * 256;
    int row = imin(i0 + (x >> 7), nrows - 1);
    e[x] = E[row * DK_ + (x & 127)];
  }
  __syncthreads();
  float acc[4] = {0,0,0,0};
  const float* eb = e + rh * 4 * 128;
  for (int k = 0; k < DK_; ++k) {
    float wv = W1[k * S_ + s];
    #pragma unroll
    for (int r = 0; r < 4; ++r) acc[r] = fmaf(eb[r * 128 + k], wv, acc[r]);
  }
  const float b1s = b1[s], w2s = W2v[s];
  float p[4];
  #pragma unroll
  for (int r = 0; r < 4; ++r) p[r] = fast_tanh(acc[r] + b1s) * w2s;
  #pragma unroll
  for (int r = 0; r < 4; ++r) p[r] = wave_sum_lane63(p[r]);
  const int lane = tid & 63;
  const int half = s >> 6;
  if (lane == 63) {
    #pragma unroll
    for (int r = 0; r < 4; ++r) red[rh * 4 + r][half] = p[r];
  }
  __syncthreads();
  if (tid < 8) {
    int i = i0 + tid;
    if (i < nrows) outt[i] = red[tid][0] + red[tid][1] + b2[0];
  }
}

// ---------------------------------------------------------------------------
#define NB_CORR 51
#define NB_EA   51
#define NB_QD   26
#define NB_SD   251
#define NB_TOT  (NB_CORR + NB_EA + NB_QD + NB_SD)

__global__ __launch_bounds__(256) void tables_kernel(
    const float* Eq, const float* Km, const float* Wsa, const float* bsa,
    float* corr_t, float* w2_t, float* csb_t,
    const float* Eqa, const float* We, const float* be,
    const float* Wa, const float* ba, float* er_t, float* ad_t,
    const float* Wqd1, const float* bqd1, const float* Wqd, const float* bqd, float* qd_t,
    const float* Es, const float* Wsd1, const float* bsd1, const float* Wsd, const float* bsd, float* sd_t)
{
  int blk = blockIdx.x;
  if (blk < NB_CORR) { corr_role(blk, Eq, Km, Wsa, bsa, corr_t, w2_t, csb_t); return; }
  blk -= NB_CORR;
  if (blk < NB_EA)   { ea_role(blk, Eqa, We, be, Wa, ba, er_t, ad_t); return; }
  blk -= NB_EA;
  if (blk < NB_QD)   { mlp_role(blk, Eq, Wqd1, bqd1, Wqd, bqd, qd_t, NQR); return; }
  blk -= NB_QD;
  mlp_role(blk, Es, Wsd1, bsd1, Wsd, bsd, sd_t, NSR);
}

// ---------------------------------------------------------------------------
// The sequential scan, v4: rows=8 per wave (overhead amortized), no LDS,
// no rotation. Grid (4, B) x 512 threads: dq = blockIdx.x (d-chunk of 64),
// wave w = mg 0..7 owns m rows mg*8..mg*8+7. 2048 waves = 2/SIMD.
// q/qa in per-lane int4 (lane l holds t=4l..4l+3), v_readlane -> SGPR
// indices -> cw loads are wave-uniform (s_load), c feeds v_fma as the
// one-SGPR operand. Two 4-step operand buffers (A/B) refilled in place.
// Per-step wave_sum via DPP; lane 63 stores float4 per 4 steps.
// ---------------------------------------------------------------------------
struct SOps { float er, ad, w2; };

static __device__ __forceinline__ void fetchg(
    int g, const int4& qq, const int4& qaq, int m0, int d,
    const float* __restrict__ corr_t, const float* __restrict__ er_t,
    const float* __restrict__ ad_t, const float* __restrict__ w2_t,
    float4 (&cA)[4], float4 (&cB)[4], SOps (&o)[4])
{
  const int q0 = __builtin_amdgcn_readlane(qq.x,  g);
  const int q1 = __builtin_amdgcn_readlane(qq.y,  g);
  const int q2 = __builtin_amdgcn_readlane(qq.z,  g);
  const int q3 = __builtin_amdgcn_readlane(qq.w,  g);
  const int a0 = __builtin_amdgcn_readlane(qaq.x, g);
  const int a1 = __builtin_amdgcn_readlane(qaq.y, g);
  const int a2 = __builtin_amdgcn_readlane(qaq.z, g);
  const int a3 = __builtin_amdgcn_readlane(qaq.w, g);
  cA[0] = *(const float4*)(corr_t + q0 * M_ + m0);
  cB[0] = *(const float4*)(corr_t + q0 * M_ + m0 + 4);
  cA[1] = *(const float4*)(corr_t + q1 * M_ + m0);
  cB[1] = *(const float4*)(corr_t + q1 * M_ + m0 + 4);
  cA[2] = *(const float4*)(corr_t + q2 * M_ + m0);
  cB[2] = *(const float4*)(corr_t + q2 * M_ + m0 + 4);
  cA[3] = *(const float4*)(corr_t + q3 * M_ + m0);
  cB[3] = *(const float4*)(corr_t + q3 * M_ + m0 + 4);
  o[0].er = er_t[a0 * DV_ + d];  o[0].ad = ad_t[a0 * DV_ + d];  o[0].w2 = w2_t[q0 * DV_ + d];
  o[1].er = er_t[a1 * DV_ + d];  o[1].ad = ad_t[a1 * DV_ + d];  o[1].w2 = w2_t[q1 * DV_ + d];
  o[2].er = er_t[a2 * DV_ + d];  o[2].ad = ad_t[a2 * DV_ + d];  o[2].w2 = w2_t[q2 * DV_ + d];
  o[3].er = er_t[a3 * DV_ + d];  o[3].ad = ad_t[a3 * DV_ + d];  o[3].w2 = w2_t[q3 * DV_ + d];
}

static __device__ __forceinline__ float stepf(
    float (&Mv)[8], const float4& ca, const float4& cb, const SOps& o)
{
  const float c[8] = {ca.x, ca.y, ca.z, ca.w, cb.x, cb.y, cb.z, cb.w};
  float r0 = c[0] * Mv[0];
  float r1 = c[1] * Mv[1];
  #pragma unroll
  for (int j = 0; j < 8; ++j) {
    if (j >= 2) {
      if (j & 1) r1 = fmaf(c[j], Mv[j], r1);   // read uses PRE-update Mv
      else       r0 = fmaf(c[j], Mv[j], r0);
    }
    const float tmp = fmaf(-o.er, Mv[j], o.ad);  // ad - er*Mv
    Mv[j] = fmaf(c[j], tmp, Mv[j]);              // Mv*(1-c*er) + c*ad
  }
  return wave_sum_lane63((r0 + r1) * o.w2);
}

__global__ __launch_bounds__(512) void scan_kernel(
    const int* __restrict__ q_data, const int* __restrict__ qa_data,
    const float* __restrict__ corr_t, const float* __restrict__ er_t,
    const float* __restrict__ ad_t, const float* __restrict__ w2_t,
    const float* __restrict__ Vm, float* __restrict__ sa_part)
{
  const int b   = blockIdx.y;
  const int dq  = blockIdx.x;    // 0..3
  const int tid = threadIdx.x;
  const int dl  = tid & 63;
  const int w   = tid >> 6;      // wave in block = m-group 0..7
  const int m0  = __builtin_amdgcn_readfirstlane(w * 8);
  const int d   = dq * 64 + dl;

  // per-lane q/qa storage: lane l holds t = 4l..4l+3
  const int4 qq  = ((const int4*)(q_data  + b * T_))[dl];
  const int4 qaq = ((const int4*)(qa_data + b * T_))[dl];

  float Mv[8];
  #pragma unroll
  for (int j = 0; j < 8; ++j) Mv[j] = Vm[(m0 + j) * DV_ + d];

  // partial layout: [p = dq*8 + mg][b][t], contiguous in t
  float* baseP = sa_part + ((dq * 8 + w) * B_ + b) * T_;

  float4 cAA[4], cBA[4], cAB[4], cBB[4];
  SOps oA[4], oB[4];
  fetchg(0, qq, qaq, m0, d, corr_t, er_t, ad_t, w2_t, cAA, cBA, oA);
  fetchg(1, qq, qaq, m0, d, corr_t, er_t, ad_t, w2_t, cAB, cBB, oB);

  for (int g = 0; g < 64; g += 2) {
    float4 pA;
    pA.x = stepf(Mv, cAA[0], cBA[0], oA[0]);
    pA.y = stepf(Mv, cAA[1], cBA[1], oA[1]);
    pA.z = stepf(Mv, cAA[2], cBA[2], oA[2]);
    pA.w = stepf(Mv, cAA[3], cBA[3], oA[3]);
    fetchg((g + 2) & 63, qq, qaq, m0, d, corr_t, er_t, ad_t, w2_t, cAA, cBA, oA);
    if (dl == 63) *(float4*)(baseP + 4 * g) = pA;

    float4 pB;
    pB.x = stepf(Mv, cAB[0], cBB[0], oB[0]);
    pB.y = stepf(Mv, cAB[1], cBB[1], oB[1]);
    pB.z = stepf(Mv, cAB[2], cBB[2], oB[2]);
    pB.w = stepf(Mv, cAB[3], cBB[3], oB[3]);
    fetchg((g + 3) & 63, qq, qaq, m0, d, corr_t, er_t, ad_t, w2_t, cAB, cBB, oB);
    if (dl == 63) *(float4*)(baseP + 4 * g + 4) = pB;
  }
}

// ---------------------------------------------------------------------------
// out[b,t] = sigmoid( 3*(sum of 32 sa partials + csb[q]) - qd[q] - sd[s] )
// sa_part layout: [p in 0..31][b][t] -> coalesced reads per p-slice.
// ---------------------------------------------------------------------------
__global__ __launch_bounds__(256) void final_kernel(
    const int* __restrict__ q_data, const int* __restrict__ s_data,
    const float* __restrict__ sa_part, const float* __restrict__ csb_t,
    const float* __restrict__ qd_t, const float* __restrict__ sd_t,
    float* __restrict__ out)
{
  const int b = blockIdx.x, t = threadIdx.x;
  float s = 0.f;
  #pragma unroll
  for (int p = 0; p < 32; ++p) s += sa_part[(p * B_ + b) * T_ + t];
  const int bt = b * T_ + t;
  const int q  = q_data[bt];
  const int si = s_data[bt];
  const float sa = s + csb_t[q];
  const float z = 3.f * sa - qd_t[q] - sd_t[si];
  out[bt] = 1.f / (1.f + __expf(-z));
}

// ---------------------------------------------------------------------------
extern "C" void kernel_launch(void* const* d_in, const int* in_sizes, int n_in,
                              void* d_out, int out_size, void* d_ws, size_t ws_size,
                              hipStream_t stream)
{
  const int*   q_data = (const int*)d_in[0];
  const int*   qa_data= (const int*)d_in[1];
  const int*   s_data = (const int*)d_in[2];
  const float* Km     = (const float*)d_in[3];
  const float* Vm     = (const float*)d_in[4];
  const float* Eq     = (const float*)d_in[5];
  const float* Eqa    = (const float*)d_in[6];
  const float* Es     = (const float*)d_in[7];
  const float* We     = (const float*)d_in[8];
  const float* be     = (const float*)d_in[9];
  const float* Wa     = (const float*)d_in[10];
  const float* ba     = (const float*)d_in[11];
  const float* Wsa    = (const float*)d_in[12];
  const float* bsa    = (const float*)d_in[13];
  const float* Wqd1   = (const float*)d_in[14];
  const float* bqd1   = (const float*)d_in[15];
  const float* Wqd    = (const float*)d_in[16];
  const float* bqd    = (const float*)d_in[17];
  const float* Wsd1   = (const float*)d_in[18];
  const float* bsd1   = (const float*)d_in[19];
  const float* Wsd    = (const float*)d_in[20];
  const float* bsd    = (const float*)d_in[21];
  float* out = (float*)d_out;

  // workspace layout (floats); total ~3.2 MB
  float* wsf    = (float*)d_ws;
  float* corr_t = wsf;                       // 201*64   = 12864
  float* w2_t   = corr_t + NQR * M_;         // 201*256  = 51456
  float* csb_t  = w2_t + NQR * DV_;          // 201 -> pad 204
  float* er_t   = csb_t + 204;               // 401*256  = 102656
  float* ad_t   = er_t + NQAR * DV_;         // 102656
  float* qd_t   = ad_t + NQAR * DV_;         // 201 -> pad 204
  float* sd_t   = qd_t + 204;                // 2001 -> pad 2004
  float* sa_p   = sd_t + 2004;               // 32*64*256 = 524288

  tables_kernel<<<NB_TOT, 256, 0, stream>>>(
      Eq, Km, Wsa, bsa, corr_t, w2_t, csb_t,
      Eqa, We, be, Wa, ba, er_t, ad_t,
      Wqd1, bqd1, Wqd, bqd, qd_t,
      Es, Wsd1, bsd1, Wsd, bsd, sd_t);
  scan_kernel<<<dim3(4, B_), 512, 0, stream>>>(q_data, qa_data, corr_t, er_t, ad_t, w2_t, Vm, sa_p);
  final_kernel<<<B_, 256, 0, stream>>>(q_data, s_data, sa_p, csb_t, qd_t, sd_t, out);
}